// Round 3
// baseline (354.866 us; speedup 1.0000x reference)
//
#include <hip/hip_runtime.h>
#include <hip/hip_bf16.h>

#define BB  32
#define LHH 1024
#define LUU 128
#define HDD 256
#define NEGF (-1e30f)

// ---- workspace layout (float offsets) ----
static constexpr size_t S_OFF    = 0;                           // [B][LH][LU] raw S
static constexpr size_t UWB_OFF  = S_OFF + (size_t)BB*LHH*LUU;  // [B][LU]
static constexpr size_t RM_OFF   = UWB_OFF + (size_t)BB*LUU;    // [B][LH] row max
static constexpr size_t RI_OFF   = RM_OFF + (size_t)BB*LHH;     // [B][LH] 1/row sum
static constexpr size_t PM_OFF   = RI_OFF + (size_t)BB*LHH;     // [B][8][LU]
static constexpr size_t PS_OFF   = PM_OFF + (size_t)BB*8*LUU;   // [B][8][LU]
static constexpr size_t CM_OFF   = PS_OFF + (size_t)BB*8*LUU;   // [B][LU] col max
static constexpr size_t CI_OFF   = CM_OFF + (size_t)BB*LUU;     // [B][LU] 1/col sum
static constexpr size_t C_OFF    = CI_OFF + (size_t)BB*LUU;     // [B][LU][HD]
static constexpr size_t FLAG_OFF = C_OFF + (size_t)BB*LUU*HDD;  // 1 int (mask dtype flag)
static constexpr size_t WS_FLOATS= FLAG_OFF + 1;

// mask accessor: flag==1 -> bool8 bytes; flag==0 -> 4-byte elements (int32 or f32 bits)
__device__ __forceinline__ float mval(const void* p, int idx, int flag) {
    if (flag) return ((const unsigned char*)p)[idx] ? 1.0f : 0.0f;
    return (((const int*)p)[idx] != 0) ? 1.0f : 0.0f;
}
// clamped exp: identity for all mathematically-contributing args (<=0), never inf
__device__ __forceinline__ float cexpf(float x) { return __expf(fminf(x, 60.0f)); }
__device__ __forceinline__ float grcp(float x)  { return 1.0f / fmaxf(x, 1e-38f); }

// ---------------- detect mask dtype ----------------
__global__ void k_detect(const unsigned char* __restrict__ hm, float* __restrict__ ws) {
    if (threadIdx.x == 0)
        reinterpret_cast<int*>(ws)[FLAG_OFF] = (hm[1] != 0) ? 1 : 0;
}

// ---------------- K0: uwb[b,j] = u[b,j,:]·w_u + bias ----------------
__global__ __launch_bounds__(256) void k_uwb(const float* __restrict__ u,
                                             const float* __restrict__ w,
                                             const float* __restrict__ bias,
                                             float* __restrict__ ws) {
    int wave = threadIdx.x >> 6;
    int lane = threadIdx.x & 63;
    int idx  = blockIdx.x * 4 + wave;          // b*LU + j
    int b = idx >> 7, j = idx & 127;
    const float4* u4  = reinterpret_cast<const float4*>(u + ((size_t)(b * LUU + j)) * HDD);
    const float4* wu4 = reinterpret_cast<const float4*>(w + HDD);
    float4 a = u4[lane], c = wu4[lane];
    float s = a.x * c.x + a.y * c.y + a.z * c.z + a.w * c.w;
    #pragma unroll
    for (int off = 32; off; off >>= 1) s += __shfl_xor(s, off);
    if (lane == 0) ws[UWB_OFF + idx] = s + bias[0];
}

// ---------------- K1: S + row softmax stats ----------------
// v[j][k] = w_h[k] + w_hu[k]*u[b,j,k], LDS 128x256 f32 with XOR float4-slot swizzle
__global__ __launch_bounds__(256) void k_S(const float* __restrict__ h,
                                           const float* __restrict__ u,
                                           const void* __restrict__ u_mask,
                                           const float* __restrict__ w,
                                           float* __restrict__ ws) {
    __shared__ float v[LUU * HDD];             // exactly 128 KiB
    int b  = blockIdx.x;
    int it = blockIdx.y;                       // i-tile of 32 rows
    int t  = threadIdx.x;
    int flag = reinterpret_cast<const int*>(ws)[FLAG_OFF];
    const float* wh  = w;
    const float* whu = w + 2 * HDD;

    // stage v (swizzled float4 slots: phys = f ^ (j&7))
    for (int e4 = t; e4 < (LUU * HDD / 4); e4 += 256) {
        int j = e4 >> 6;
        int f = e4 & 63;
        int k4 = f * 4;
        float4 uu = *reinterpret_cast<const float4*>(u + ((size_t)(b * LUU + j)) * HDD + k4);
        float4 a  = *reinterpret_cast<const float4*>(wh + k4);
        float4 c  = *reinterpret_cast<const float4*>(whu + k4);
        float4 vv = make_float4(a.x + c.x * uu.x, a.y + c.y * uu.y,
                                a.z + c.z * uu.z, a.w + c.w * uu.w);
        *reinterpret_cast<float4*>(&v[j * 256 + ((f ^ (j & 7)) << 2)]) = vv;
    }
    __syncthreads();

    int wave = t >> 6, lane = t & 63;
    int row0 = it * 32 + wave * 8;
    const float* hbase = h + ((size_t)(b * LHH + row0)) * HDD;
    float um0 = mval(u_mask, b * LUU + lane, flag);
    float um1 = mval(u_mask, b * LUU + lane + 64, flag);
    float uw0 = ws[UWB_OFF + b * LUU + lane];
    float uw1 = ws[UWB_OFF + b * LUU + lane + 64];

    float acc0[8], acc1[8];
    #pragma unroll
    for (int r = 0; r < 8; ++r) { acc0[r] = 0.f; acc1[r] = 0.f; }

    int sw = lane & 7;                         // (lane+64)&7 == lane&7
    const float* vp0 = v + lane * 256;
    const float* vp1 = v + (lane + 64) * 256;
    #pragma unroll 4
    for (int k4 = 0; k4 < 64; ++k4) {
        int o = (k4 ^ sw) << 2;                // physical slot holding logical chunk k4
        float4 v0 = *reinterpret_cast<const float4*>(vp0 + o);
        float4 v1 = *reinterpret_cast<const float4*>(vp1 + o);
        int kk = k4 * 4;                       // FIX: logical k index (was (k4^sw)*4)
        #pragma unroll
        for (int r = 0; r < 8; ++r) {
            float4 hv = *reinterpret_cast<const float4*>(hbase + (size_t)r * HDD + kk);
            acc0[r] += hv.x * v0.x + hv.y * v0.y + hv.z * v0.z + hv.w * v0.w;
            acc1[r] += hv.x * v1.x + hv.y * v1.y + hv.z * v1.z + hv.w * v1.w;
        }
    }

    #pragma unroll
    for (int r = 0; r < 8; ++r) {
        int row = row0 + r;
        float S0 = acc0[r] + uw0;
        float S1 = acc1[r] + uw1;
        float* Srow = ws + S_OFF + ((size_t)(b * LHH + row)) * LUU;
        Srow[lane] = S0;
        Srow[lane + 64] = S1;
        float ms = fmaxf(um0 > 0.f ? S0 : NEGF, um1 > 0.f ? S1 : NEGF);
        #pragma unroll
        for (int off = 32; off; off >>= 1) ms = fmaxf(ms, __shfl_xor(ms, off));
        float e = um0 * cexpf(S0 - ms) + um1 * cexpf(S1 - ms);
        #pragma unroll
        for (int off = 32; off; off >>= 1) e += __shfl_xor(e, off);
        if (lane == 0) {
            ws[RM_OFF + b * LHH + row] = ms;
            ws[RI_OFF + b * LHH + row] = grcp(e);
        }
    }
}

// ---------------- K2: partial column stats ----------------
__global__ __launch_bounds__(256) void k_colpart(const void* __restrict__ h_mask,
                                                 float* __restrict__ ws) {
    int b = blockIdx.x, c = blockIdx.y;        // chunk of 128 i
    int t = threadIdx.x;
    int j = t & 127, ih = t >> 7;
    int flag = reinterpret_cast<const int*>(ws)[FLAG_OFF];
    float m = NEGF, s = 0.f;
    const float* Sb = ws + S_OFF + ((size_t)b * LHH) * LUU;
    int i0 = c * 128;
    for (int ii = ih; ii < 128; ii += 2) {
        int i = i0 + ii;
        if (mval(h_mask, b * LHH + i, flag) > 0.f) {
            float x  = Sb[(size_t)i * LUU + j];
            float mn = fmaxf(m, x);
            s = s * __expf(m - mn) + __expf(x - mn);
            m = mn;
        }
    }
    __shared__ float sm_m[128], sm_s[128];
    if (ih == 0) { sm_m[j] = m; sm_s[j] = s; }
    __syncthreads();
    if (ih == 1) {
        float m0 = sm_m[j], s0 = sm_s[j];
        float mn = fmaxf(m0, m);
        float sc = s0 * __expf(fminf(m0 - mn, 0.f)) + s * __expf(fminf(m - mn, 0.f));
        ws[PM_OFF + (b * 8 + c) * LUU + j] = mn;
        ws[PS_OFF + (b * 8 + c) * LUU + j] = sc;
    }
}

// ---------------- K2b: combine partial column stats ----------------
__global__ __launch_bounds__(128) void k_colcomb(float* __restrict__ ws) {
    int b = blockIdx.x, j = threadIdx.x;
    float m = NEGF;
    #pragma unroll
    for (int c = 0; c < 8; ++c) m = fmaxf(m, ws[PM_OFF + (b * 8 + c) * LUU + j]);
    float s = 0.f;
    #pragma unroll
    for (int c = 0; c < 8; ++c)
        s += ws[PS_OFF + (b * 8 + c) * LUU + j] * cexpf(ws[PM_OFF + (b * 8 + c) * LUU + j] - m);
    ws[CM_OFF + b * LUU + j] = m;
    ws[CI_OFF + b * LUU + j] = grcp(s);
}

// ---------------- K3: C[b,q,:] = sum_i a_t[i,q] * h[b,i,:] ----------------
__global__ __launch_bounds__(256) void k_C(const float* __restrict__ h,
                                           const void* __restrict__ u_mask,
                                           float* __restrict__ ws) {
    int b = blockIdx.x, ut = blockIdx.y;       // u-tile of 16
    int u0 = ut * 16;
    int t = threadIdx.x;
    int flag = reinterpret_cast<const int*>(ws)[FLAG_OFF];
    __shared__ float a_l[64][16];
    float acc[16];
    #pragma unroll
    for (int q = 0; q < 16; ++q) acc[q] = 0.f;

    const float* Sb = ws + S_OFF + (size_t)b * LHH * LUU;
    const float* rm = ws + RM_OFF + b * LHH;
    const float* ri = ws + RI_OFF + b * LHH;
    const float* hb = h + (size_t)b * LHH * HDD;

    int iq = t >> 2, uq = t & 3;
    float um_[4];
    #pragma unroll
    for (int c = 0; c < 4; ++c)
        um_[c] = mval(u_mask, b * LUU + u0 + uq * 4 + c, flag);

    for (int i0 = 0; i0 < LHH; i0 += 64) {
        __syncthreads();
        {
            int i = i0 + iq;
            float4 s4 = *reinterpret_cast<const float4*>(Sb + (size_t)i * LUU + u0 + uq * 4);
            float mm = rm[i], rr = ri[i];
            a_l[iq][uq * 4 + 0] = um_[0] * cexpf(s4.x - mm) * rr;
            a_l[iq][uq * 4 + 1] = um_[1] * cexpf(s4.y - mm) * rr;
            a_l[iq][uq * 4 + 2] = um_[2] * cexpf(s4.z - mm) * rr;
            a_l[iq][uq * 4 + 3] = um_[3] * cexpf(s4.w - mm) * rr;
        }
        __syncthreads();
        #pragma unroll 4
        for (int ii = 0; ii < 64; ++ii) {
            float hval = hb[(size_t)(i0 + ii) * HDD + t];
            #pragma unroll
            for (int q = 0; q < 4; ++q) {
                float4 a4 = *reinterpret_cast<const float4*>(&a_l[ii][q * 4]);
                acc[q * 4 + 0] += a4.x * hval;
                acc[q * 4 + 1] += a4.y * hval;
                acc[q * 4 + 2] += a4.z * hval;
                acc[q * 4 + 3] += a4.w * hval;
            }
        }
    }
    #pragma unroll
    for (int q = 0; q < 16; ++q)
        ws[C_OFF + ((size_t)(b * LUU + u0 + q)) * HDD + t] = acc[q];
}

// ---------------- K4: U_tilde, H_tilde, output concat ----------------
__global__ __launch_bounds__(256) void k_out(const float* __restrict__ h,
                                             const float* __restrict__ u,
                                             const void* __restrict__ h_mask,
                                             const void* __restrict__ u_mask,
                                             const float* __restrict__ ws,
                                             float* __restrict__ out) {
    int b = blockIdx.x, itile = blockIdx.y;    // tiles of 16 rows
    int i0 = itile * 16;
    int t = threadIdx.x;
    int flag = reinterpret_cast<const int*>(ws)[FLAG_OFF];
    __shared__ float aT[128][16], bT[128][16];
    __shared__ float cm_l[128], ci_l[128], um_l[128];
    __shared__ float rm_l[16], ri_l[16], hm_l[16];

    if (t < 128) {
        cm_l[t] = ws[CM_OFF + b * LUU + t];
        ci_l[t] = ws[CI_OFF + b * LUU + t];
        um_l[t] = mval(u_mask, b * LUU + t, flag);
    } else if (t < 144) {
        int r = t - 128;
        rm_l[r] = ws[RM_OFF + b * LHH + i0 + r];
        ri_l[r] = ws[RI_OFF + b * LHH + i0 + r];
        hm_l[r] = mval(h_mask, b * LHH + i0 + r, flag);
    }
    __syncthreads();

    {
        int j4 = t & 31, rp = t >> 5;          // rp in [0,8)
        #pragma unroll
        for (int half = 0; half < 2; ++half) {
            int r = rp + half * 8;
            int i = i0 + r;
            float4 s4 = *reinterpret_cast<const float4*>(
                ws + S_OFF + ((size_t)(b * LHH + i)) * LUU + j4 * 4);
            float mm = rm_l[r], rr = ri_l[r], hm = hm_l[r];
            float xs[4] = {s4.x, s4.y, s4.z, s4.w};
            #pragma unroll
            for (int c = 0; c < 4; ++c) {
                int j = j4 * 4 + c;
                aT[j][r] = um_l[j] * cexpf(xs[c] - mm) * rr;
                bT[j][r] = hm * cexpf(xs[c] - cm_l[j]) * ci_l[j];
            }
        }
    }
    __syncthreads();

    float accU[16], accH[16];
    #pragma unroll
    for (int r = 0; r < 16; ++r) { accU[r] = 0.f; accH[r] = 0.f; }

    const float* ub = u + (size_t)b * LUU * HDD;
    const float* Cb = ws + C_OFF + (size_t)b * LUU * HDD;

    #pragma unroll 2
    for (int j = 0; j < LUU; ++j) {
        float uval = ub[(size_t)j * HDD + t];
        float cval = Cb[(size_t)j * HDD + t];
        #pragma unroll
        for (int q = 0; q < 4; ++q) {
            float4 a4 = *reinterpret_cast<const float4*>(&aT[j][q * 4]);
            float4 b4 = *reinterpret_cast<const float4*>(&bT[j][q * 4]);
            accU[q * 4 + 0] += a4.x * uval;
            accU[q * 4 + 1] += a4.y * uval;
            accU[q * 4 + 2] += a4.z * uval;
            accU[q * 4 + 3] += a4.w * uval;
            accH[q * 4 + 0] += b4.x * cval;
            accH[q * 4 + 1] += b4.y * cval;
            accH[q * 4 + 2] += b4.z * cval;
            accH[q * 4 + 3] += b4.w * cval;
        }
    }

    #pragma unroll
    for (int r = 0; r < 16; ++r) {
        int i = i0 + r;
        float hval = h[((size_t)(b * LHH + i)) * HDD + t];
        size_t base = ((size_t)(b * LHH + i)) * (4 * HDD) + t;
        out[base]           = hval;
        out[base + HDD]     = accU[r];
        out[base + 2 * HDD] = hval * accU[r];
        out[base + 3 * HDD] = hval * accH[r];
    }
}

extern "C" void kernel_launch(void* const* d_in, const int* in_sizes, int n_in,
                              void* d_out, int out_size, void* d_ws, size_t ws_size,
                              hipStream_t stream) {
    const float* h = (const float*)d_in[0];
    const float* u = (const float*)d_in[1];
    const void*  h_mask = d_in[2];
    const void*  u_mask = d_in[3];
    const float* w    = (const float*)d_in[4];
    const float* bias = (const float*)d_in[5];
    float* ws  = (float*)d_ws;
    float* out = (float*)d_out;

    if (ws_size < WS_FLOATS * sizeof(float)) return;  // diagnostic: leaves out zeroed

    k_detect<<<dim3(1), 64, 0, stream>>>((const unsigned char*)h_mask, ws);
    k_uwb<<<dim3(BB * LUU / 4), 256, 0, stream>>>(u, w, bias, ws);
    k_S<<<dim3(BB, LHH / 32), 256, 0, stream>>>(h, u, u_mask, w, ws);
    k_colpart<<<dim3(BB, 8), 256, 0, stream>>>(h_mask, ws);
    k_colcomb<<<dim3(BB), 128, 0, stream>>>(ws);
    k_C<<<dim3(BB, LUU / 16), 256, 0, stream>>>(h, u_mask, ws);
    k_out<<<dim3(BB, LHH / 16), 256, 0, stream>>>(h, u, h_mask, u_mask, ws, out);
}